// Round 6
// baseline (76.623 us; speedup 1.0000x reference)
//
#include <hip/hip_runtime.h>
#include <stdint.h>

#define BATCH 2048
#define INF 1024
#define OUTF 1024
#define GRID_G 8
#define KTOT 9216   // INF + INF*GRID_G

#define BM 256
#define BN 256
#define BK 64
#define SK 8
#define KC (KTOT / SK)   // 1152
#define NKT (KC / BK)    // 18
#define MTT (BATCH / BM) // 8
#define NTT (OUTF / BN)  // 4
#define CSLAB ((size_t)BATCH * OUTF)

typedef __attribute__((ext_vector_type(8))) short short8_t;
typedef __attribute__((ext_vector_type(4))) float f32x4_t;
typedef __attribute__((ext_vector_type(8))) unsigned short u16x8_t;

__device__ __forceinline__ unsigned short f2bf(float f) {
  unsigned int u = __float_as_uint(f);
  u += 0x7FFFu + ((u >> 16) & 1u);
  return (unsigned short)(u >> 16);
}

__device__ __forceinline__ void async16(void* lds, const void* g) {
  __builtin_amdgcn_global_load_lds(
      (const __attribute__((address_space(1))) void*)g,
      (__attribute__((address_space(3))) void*)lds, 16, 0, 0);
}

// Build W_cat[o][k]: k<1024 -> bf16(base_weight[o][k]); else bf16(coeff[o][k-1024])
__global__ __launch_bounds__(256) void build_w_kernel(
    const float* __restrict__ bw, const float* __restrict__ coeff,
    unsigned short* __restrict__ wc) {
  int id = blockIdx.x * 256 + threadIdx.x;  // one thread per 8 elements
  int row = id / (KTOT / 8);
  int k8 = id - row * (KTOT / 8);
  int k = k8 * 8;
  const float* src = (k < INF) ? (bw + (size_t)row * INF + k)
                               : (coeff + (size_t)row * (INF * GRID_G) + (k - INF));
  const float4* s4 = (const float4*)src;
  float4 a = s4[0], b = s4[1];
  u16x8_t v;
  v[0] = f2bf(a.x); v[1] = f2bf(a.y); v[2] = f2bf(a.z); v[3] = f2bf(a.w);
  v[4] = f2bf(b.x); v[5] = f2bf(b.y); v[6] = f2bf(b.z); v[7] = f2bf(b.w);
  *(u16x8_t*)(wc + (size_t)id * 8) = v;
}

// Build A_cat[b][k]: k<1024 -> bf16(x[b][k]); spline block: one-hot(idx)*bf16(0.1*w)
__global__ __launch_bounds__(256) void build_a_kernel(
    const float* __restrict__ x, const float* __restrict__ grid,
    unsigned short* __restrict__ ac) {
  __shared__ float sg[GRID_G + 1];
  if (threadIdx.x <= GRID_G) sg[threadIdx.x] = grid[threadIdx.x];
  __syncthreads();
  int id = blockIdx.x * 256 + threadIdx.x;  // one per (b,i)
  int b = id >> 10;
  int i = id & 1023;
  float xv = x[id];
  ac[(size_t)b * KTOT + i] = f2bf(xv);
  float xc = fminf(fmaxf(xv, -1.0f), 1.0f);
  int cnt = 0;
#pragma unroll
  for (int j = 0; j <= GRID_G; ++j) cnt += (xc >= sg[j]) ? 1 : 0;
  int idx = cnt - 1;
  idx = idx < 0 ? 0 : (idx > GRID_G - 1 ? GRID_G - 1 : idx);
  float left = sg[idx], right = sg[idx + 1];
  float denom = right - left;
  denom = (denom == 0.0f) ? 1.0f : denom;
  float w = (xc - left) / denom;
  unsigned short val = f2bf(0.1f * w);
  u16x8_t v;
#pragma unroll
  for (int g = 0; g < GRID_G; ++g) v[g] = (g == idx) ? val : (unsigned short)0;
  *(u16x8_t*)(ac + (size_t)b * KTOT + INF + (size_t)i * 8) = v;
}

// 256x256x(BK=64) split-K GEMM, 4-phase counted-vmcnt pipeline, raw barriers,
// setprio, chunk-TRANSPOSED LDS blocks for conflict-free ds_read_b128.
//
// LDS region (per buf,ks): 256 rows x 32 cols bf16 = 16 KB = 16 blocks of
// 1024 B (16 rows x 4 sixteen-byte chunks). Within block g, semantic
// (row r = 16g+lr, chunk k) lives at physical chunk k*16+lr (chunk-transpose).
// Realized via per-lane GLOBAL source permutation (linear global_load_lds
// dest): lane l of wave w sources row w*16+(l&15), chunk (l>>4).
// A frag-read ds_read_b128's 16-lane group (rows 0..15, fixed k) then reads
// 256 CONTIGUOUS bytes -> 32 banks x 2 lanes = conflict-free.
//
// Per iteration t (tile t in buf c=t&1):
//   gate[vmcnt(4)] -> read k0 frags; stage A(k0,t+1), B(k0,t+1); 2x16 MFMA
//   gate[vmcnt(4)] -> read k1 frags; stage A(k1,t+1), B(k1,t+1); 2x16 MFMA
// Steady state: the 4 oldest outstanding loads at each gate are exactly the
// half-tiles needed next, issued one full iteration earlier. Tail: vmcnt(0).
__global__ __launch_bounds__(512, 2) void gemm_kernel(
    const unsigned short* __restrict__ A, const unsigned short* __restrict__ W,
    unsigned short* __restrict__ P) {
  __shared__ unsigned short LA[2][2][256 * 32];  // 64 KB
  __shared__ unsigned short LB[2][2][256 * 32];  // 64 KB

  int bid = blockIdx.x;
  int sk = bid & 7;          // XCD affinity: one sk-slab per XCD
  int t0 = bid >> 3;         // 0..31
  int mt = t0 >> 2;          // 0..7
  int nt = t0 & 3;           // 0..3

  int tid = threadIdx.x;
  int wave = tid >> 6;
  int lane = tid & 63;
  int wr = wave >> 2, wc = wave & 3;   // 2x4 wave grid; per-wave C = 128x64
  int lr = lane & 15, lk = lane >> 4;
  // chunk-transposed per-lane read offset (elements) within a 512-elem block
  int rlo = lk * 128 + lr * 8;

  // staging source (chunk-transpose): lane l -> row w*16+(l&15), chunk l>>4
  int srow = (tid >> 6) * 16 + (tid & 15);
  int scol = ((tid >> 4) & 3) * 8;
  const unsigned short* gA  = A + (size_t)(mt * BM + srow) * KTOT + sk * KC + scol;
  const unsigned short* gA2 = gA + (size_t)128 * KTOT;
  const unsigned short* gB  = W + (size_t)(nt * BN + srow) * KTOT + sk * KC + scol;
  const unsigned short* gB2 = gB + (size_t)128 * KTOT;

  f32x4_t acc[2][4][4];
#pragma unroll
  for (int ch = 0; ch < 2; ++ch)
#pragma unroll
    for (int mf = 0; mf < 4; ++mf)
#pragma unroll
      for (int nf = 0; nf < 4; ++nf) acc[ch][mf][nf] = f32x4_t{0.f, 0.f, 0.f, 0.f};

#define STAGE_A(nb, ks_, tt) { \
    unsigned short* d_ = &LA[nb][ks_][wave * 512]; \
    async16(d_, gA + (tt) * BK + (ks_) * 32); \
    async16(d_ + 4096, gA2 + (tt) * BK + (ks_) * 32); }
#define STAGE_B(nb, ks_, tt) { \
    unsigned short* d_ = &LB[nb][ks_][wave * 512]; \
    async16(d_, gB + (tt) * BK + (ks_) * 32); \
    async16(d_ + 4096, gB2 + (tt) * BK + (ks_) * 32); }
#define LOAD_BF(ks_) { _Pragma("unroll") for (int nf = 0; nf < 4; ++nf) \
    bfr[nf] = *(const short8_t*)&LB[c][ks_][(wc * 4 + nf) * 512 + rlo]; }
#define LOAD_AF(ks_, ch_) { _Pragma("unroll") for (int mf = 0; mf < 4; ++mf) \
    afr[mf] = *(const short8_t*)&LA[c][ks_][(wr * 8 + (ch_) * 4 + mf) * 512 + rlo]; }
#define DO_MFMA(ch_) { __builtin_amdgcn_s_setprio(1); \
    _Pragma("unroll") for (int mf = 0; mf < 4; ++mf) \
    _Pragma("unroll") for (int nf = 0; nf < 4; ++nf) \
      acc[ch_][mf][nf] = __builtin_amdgcn_mfma_f32_16x16x32_bf16( \
          afr[mf], bfr[nf], acc[ch_][mf][nf], 0, 0, 0); \
    __builtin_amdgcn_s_setprio(0); }
#define GATE(pf_) { if (pf_) asm volatile("s_waitcnt vmcnt(4)" ::: "memory"); \
    else asm volatile("s_waitcnt vmcnt(0)" ::: "memory"); \
    __builtin_amdgcn_s_barrier(); \
    asm volatile("" ::: "memory"); }

  // prologue: tile 0 into buf 0, issue order A(k0) B(k0) A(k1) B(k1)
  STAGE_A(0, 0, 0) STAGE_B(0, 0, 0) STAGE_A(0, 1, 0) STAGE_B(0, 1, 0)

  for (int t = 0; t < NKT; ++t) {
    int c = t & 1, nb = c ^ 1;
    int tn = t + 1;
    bool pf = tn < NKT;
    short8_t afr[4], bfr[4];

    GATE(pf)                       // ensures A(k0,t), B(k0,t) landed (all waves)
    LOAD_AF(0, 0) LOAD_BF(0)
    if (pf) STAGE_A(nb, 0, tn)
    DO_MFMA(0)
    LOAD_AF(0, 1)
    if (pf) STAGE_B(nb, 0, tn)
    DO_MFMA(1)

    GATE(pf)                       // ensures A(k1,t), B(k1,t) landed
    LOAD_AF(1, 0) LOAD_BF(1)
    if (pf) STAGE_A(nb, 1, tn)
    DO_MFMA(0)
    LOAD_AF(1, 1)
    if (pf) STAGE_B(nb, 1, tn)
    DO_MFMA(1)
  }

  // epilogue: C/D col=lane&15 (n), row=(lane>>4)*4+reg (m); private bf16 slab
  unsigned short* slab = P + (size_t)sk * CSLAB;
#pragma unroll
  for (int ch = 0; ch < 2; ++ch)
#pragma unroll
    for (int mf = 0; mf < 4; ++mf)
#pragma unroll
      for (int nf = 0; nf < 4; ++nf) {
        int col = nt * BN + wc * 64 + nf * 16 + lr;
        int rowb = mt * BM + wr * 128 + ch * 64 + mf * 16 + lk * 4;
#pragma unroll
        for (int r = 0; r < 4; ++r)
          slab[(size_t)(rowb + r) * OUTF + col] = f2bf(acc[ch][mf][nf][r]);
      }
}

// out[e] = sum_sk P[sk][e]; 8 elements/thread, fully overwrites d_out.
__global__ __launch_bounds__(256) void reduce_kernel(
    const unsigned short* __restrict__ P, float* __restrict__ out) {
  size_t base = ((size_t)blockIdx.x * 256 + threadIdx.x) * 8;
  float s[8];
#pragma unroll
  for (int j = 0; j < 8; ++j) s[j] = 0.0f;
#pragma unroll
  for (int k = 0; k < SK; ++k) {
    u16x8_t v = *(const u16x8_t*)(P + (size_t)k * CSLAB + base);
#pragma unroll
    for (int j = 0; j < 8; ++j)
      s[j] += __uint_as_float((unsigned int)v[j] << 16);
  }
  float4 lo = {s[0], s[1], s[2], s[3]};
  float4 hi = {s[4], s[5], s[6], s[7]};
  *(float4*)(out + base) = lo;
  *(float4*)(out + base + 4) = hi;
}

extern "C" void kernel_launch(void* const* d_in, const int* in_sizes, int n_in,
                              void* d_out, int out_size, void* d_ws, size_t ws_size,
                              hipStream_t stream) {
  const float* x = (const float*)d_in[0];
  const float* bw = (const float*)d_in[1];
  const float* coeff = (const float*)d_in[2];
  const float* grid = (const float*)d_in[3];
  float* out = (float*)d_out;

  unsigned short* Acat = (unsigned short*)d_ws;              // 37.75 MB
  unsigned short* Wcat = Acat + (size_t)BATCH * KTOT;        // 18.87 MB
  unsigned short* Part = Wcat + (size_t)OUTF * KTOT;         // 33.55 MB

  build_w_kernel<<<OUTF * (KTOT / 8) / 256, 256, 0, stream>>>(bw, coeff, Wcat);
  build_a_kernel<<<BATCH * INF / 256, 256, 0, stream>>>(x, grid, Acat);
  gemm_kernel<<<SK * MTT * NTT, 512, 0, stream>>>(Acat, Wcat, Part);
  reduce_kernel<<<(int)(CSLAB / 8 / 256), 256, 0, stream>>>(Part, out);
}